// Round 14
// baseline (228.910 us; speedup 1.0000x reference)
//
#include <hip/hip_runtime.h>
#include <hip/hip_bf16.h>

// SIREN + Fourier-features fused forward, MI355X (gfx950). Round 14.
// = round 12 (203us; stagger of r13 reverted) with the layer body
// restructured jt-major: per jt, 32 MFMAs then immediately that jt's
// sin-epilogue into registers (hold[jt]) — no barrier between, so jt's
// VALU/trans hides under jt+1's MFMAs (3/4 of epilogue hidden). LDS
// writes (pre-packed b64) happen after bar2 as before. hf re-read per jt.

typedef __attribute__((ext_vector_type(8))) short bf16x8;
typedef __attribute__((ext_vector_type(4))) float f32x4;

#define NTOTAL 262144
#define BM 64
#define HD 256
#define INV2PI 0.15915494309189535f

__device__ __forceinline__ unsigned short f2bf(float f) {
    unsigned int u = __float_as_uint(f);
    u += 0x7FFFu + ((u >> 16) & 1u);   // RNE (convert kernel only)
    return (unsigned short)(u >> 16);
}

// pack two floats -> 2xbf16 in one u32 (low = a, high = b), compiler-backed
__device__ __forceinline__ unsigned int pk2(float a, float b) {
    __hip_bfloat162 h = __float22bfloat162_rn(make_float2(a, b));
    union { __hip_bfloat162 h; unsigned int u; } c;
    c.h = h;
    return c.u;
}

__device__ __forceinline__ float sin_rev(float rev) {   // sin(2*pi*rev)
    return __builtin_amdgcn_sinf(__builtin_amdgcn_fractf(rev));
}

// swizzled byte offset into the [64][256] bf16 LDS tile (row stride 512B).
// XOR spans bits 4-7: bijective per row; write conflicts 2-way (free).
__device__ __forceinline__ int a_off(int r, int byte) {
    return r * 512 + (byte ^ ((r & 15) << 4));
}

// ---------------- kernel 1: weight conversion + fragment packing ----------------
// wb layout (bf16 elems): 5 layers x 65536, each as 128 fragments x 512 elems.
// fragidx = jt_global*8 + kt; within-fragment elem = (q*16 + r)*8 + t, where
// j = jt_global*16 + r, k = kt*32 + q*8 + t. Then Wf row-major 16x256 zero-pad.
// Layer-0 weights pre-scaled by sqrt(2) (Fourier feature scale folded in).
__global__ void convert_w(const float* __restrict__ W0, const float* __restrict__ Wh,
                          const float* __restrict__ Wf, unsigned short* __restrict__ wb) {
    const int i = blockIdx.x * 256 + threadIdx.x;      // grid 1280 -> 327680
    if (i < 327680) {
        const int l = i >> 16, rem = i & 65535;
        const int j = rem >> 8, k = rem & 255;
        const float v = (l == 0) ? W0[rem] * 1.41421356237309515f : Wh[i - 65536];
        const int jt = j >> 4, kt = k >> 5, q = (k >> 3) & 3, r = j & 15, t = k & 7;
        const int dst = (l << 16) + (((jt << 3) + kt) << 9) + (((q << 4) + r) << 3) + t;
        wb[dst] = f2bf(v);
    }
    if (i < 4096)
        wb[327680 + i] = (i < 512) ? f2bf(Wf[i]) : (unsigned short)0;
}

// ---------------- kernel 2: fused model ----------------
__global__ __launch_bounds__(256, 3) void siren_fused(
    const float* __restrict__ x, const float* __restrict__ scales,
    const float* __restrict__ Bm, const float* __restrict__ b0,
    const float* __restrict__ bh, const float* __restrict__ bfin,
    const unsigned short* __restrict__ wb, float* __restrict__ out) {

    __shared__ __align__(16) unsigned short A[BM * HD];

    const int tid  = threadIdx.x;
    const int lane = tid & 63;
    const int wid  = tid >> 6;          // wave 0..3 owns neurons wid*64..+63
    const int row0 = blockIdx.x * BM;
    const int arow = lane & 15;
    const int q    = lane >> 4;         // 0..3
    const int kq   = q * 8;

    // ---- Fourier feature stage (fp32; sqrt2 folded into W0) ----
    {
        const int r  = tid >> 2;            // 0..63
        const int c0 = (tid & 3) * 32;      // 32 freqs per thread
        const float* xr = x + (row0 + r) * 3;
        const float x0 = xr[0] * scales[0] * INV2PI;
        const float x1 = xr[1] * scales[1] * INV2PI;
        const float x2 = xr[2] * scales[2] * INV2PI;
        #pragma unroll
        for (int cc = 0; cc < 32; cc += 8) {
            const int c = c0 + cc;
            float sv[8], cv[8];
            #pragma unroll
            for (int t = 0; t < 8; ++t) {
                const float rev = x0 * Bm[c + t] + x1 * Bm[128 + c + t] + x2 * Bm[256 + c + t];
                const float fr  = __builtin_amdgcn_fractf(rev);
                sv[t] = __builtin_amdgcn_sinf(fr);
                cv[t] = __builtin_amdgcn_cosf(fr);
            }
            uint4 us, uc;
            us.x = pk2(sv[0], sv[1]); us.y = pk2(sv[2], sv[3]);
            us.z = pk2(sv[4], sv[5]); us.w = pk2(sv[6], sv[7]);
            uc.x = pk2(cv[0], cv[1]); uc.y = pk2(cv[2], cv[3]);
            uc.z = pk2(cv[4], cv[5]); uc.w = pk2(cv[6], cv[7]);
            *(uint4*)((char*)A + a_off(r, 2 * c))         = us;
            *(uint4*)((char*)A + a_off(r, 2 * (c + 128))) = uc;
        }
    }

    // ---- 5 dense layers, jt-major with fused per-jt epilogue ----
    #pragma unroll 1
    for (int layer = 0; layer < 5; ++layer) {
        const unsigned short* Wl = wb + (layer << 16);
        const float s = (layer == 0) ? (30.0f * INV2PI) : INV2PI;
        const float* bias = (layer == 0) ? b0 : (bh + (layer - 1) * HD);

        __syncthreads();   // bar1: h tile ready

        uint2 hold[4][4];      // packed bf16 results per (jt, rt)
        f32x4 acc[4];          // accumulators for the current jt
        bf16x8 wfbuf[2], hfbuf[2][4];

        // prologue: load step u=0 (jt=0, kt=0)
        wfbuf[0] = *(const bf16x8*)(Wl + (((wid * 4) << 3) << 9) + lane * 8);
        #pragma unroll
        for (int rt = 0; rt < 4; ++rt)
            hfbuf[0][rt] = *(const bf16x8*)((const char*)A +
                a_off(rt * 16 + arow, q * 16));

        #pragma unroll
        for (int u = 0; u < 32; ++u) {
            const int jt = u >> 3, kt = u & 7;
            const int cur = u & 1, nxt = cur ^ 1;
            if (kt == 0) {
                #pragma unroll
                for (int rt = 0; rt < 4; ++rt) acc[rt] = (f32x4)(0.0f);
            }
            if (u < 31) {   // prefetch step u+1 (depth-1 ping-pong)
                const int jt1 = (u + 1) >> 3, kt1 = (u + 1) & 7;
                wfbuf[nxt] = *(const bf16x8*)(Wl +
                    ((((wid * 4 + jt1) << 3) + kt1) << 9) + lane * 8);
                #pragma unroll
                for (int rt = 0; rt < 4; ++rt)
                    hfbuf[nxt][rt] = *(const bf16x8*)((const char*)A +
                        a_off(rt * 16 + arow, kt1 * 64 + q * 16));
            }
            #pragma unroll
            for (int rt = 0; rt < 4; ++rt)
                acc[rt] = __builtin_amdgcn_mfma_f32_16x16x32_bf16(
                    wfbuf[cur], hfbuf[cur][rt], acc[rt], 0, 0, 0);
            if (kt == 7) {   // this jt done -> fused epilogue into registers;
                             // its VALU hides under next jt's MFMAs (no barrier)
                const int jj = wid * 64 + jt * 16 + q * 4;
                float4 bv = *(const float4*)(bias + jj);
                bv.x *= s; bv.y *= s; bv.z *= s; bv.w *= s;
                #pragma unroll
                for (int rt = 0; rt < 4; ++rt) {
                    const float s0 = sin_rev(fmaf(acc[rt][0], s, bv.x));
                    const float s1 = sin_rev(fmaf(acc[rt][1], s, bv.y));
                    const float s2 = sin_rev(fmaf(acc[rt][2], s, bv.z));
                    const float s3 = sin_rev(fmaf(acc[rt][3], s, bv.w));
                    hold[jt][rt].x = pk2(s0, s1);
                    hold[jt][rt].y = pk2(s2, s3);
                }
            }
        }

        __syncthreads();   // bar2: all reads of h done; safe to overwrite

        #pragma unroll
        for (int jt = 0; jt < 4; ++jt) {
            const int jj = wid * 64 + jt * 16 + q * 4;
            #pragma unroll
            for (int rt = 0; rt < 4; ++rt)
                *(uint2*)((char*)A + a_off(rt * 16 + arow, jj * 2)) = hold[jt][rt];
        }
    }

    __syncthreads();   // final h ready

    // ---- final linear 256 -> 2, distributed: wave w handles rows w*16..+15 ----
    {
        const unsigned short* Wfp = wb + 327680;   // row-major [16][256], zero-padded
        f32x4 acc = (f32x4)(0.0f);
        #pragma unroll
        for (int kt = 0; kt < 8; ++kt) {
            const bf16x8 ff = *(const bf16x8*)(Wfp + arow * HD + kt * 32 + kq);
            const bf16x8 hf = *(const bf16x8*)((const char*)A +
                a_off(wid * 16 + arow, kt * 64 + q * 16));
            acc = __builtin_amdgcn_mfma_f32_16x16x32_bf16(ff, hf, acc, 0, 0, 0);
        }
        if (q == 0) {   // lanes 0-15 hold D rows j=0..3; j=0,1 are the two outputs
            const int rg = row0 + wid * 16 + arow;
            float2 o;
            o.x = acc[0] + bfin[0];
            o.y = acc[1] + bfin[1];
            *(float2*)(out + rg * 2) = o;
        }
    }
}

extern "C" void kernel_launch(void* const* d_in, const int* in_sizes, int n_in,
                              void* d_out, int out_size, void* d_ws, size_t ws_size,
                              hipStream_t stream) {
    (void)in_sizes; (void)n_in; (void)out_size; (void)ws_size;
    const float* x      = (const float*)d_in[0];
    const float* scales = (const float*)d_in[1];
    const float* Bm     = (const float*)d_in[2];
    const float* W0     = (const float*)d_in[3];
    const float* b0     = (const float*)d_in[4];
    const float* Wh     = (const float*)d_in[5];
    const float* bh     = (const float*)d_in[6];
    const float* Wf     = (const float*)d_in[7];
    const float* bf     = (const float*)d_in[8];
    unsigned short* wb  = (unsigned short*)d_ws;   // needs 663552 B

    hipLaunchKernelGGL(convert_w, dim3(1280), dim3(256), 0, stream, W0, Wh, Wf, wb);
    hipLaunchKernelGGL(siren_fused, dim3(NTOTAL / BM), dim3(256), 0, stream,
                       x, scales, Bm, b0, bh, bf, wb, (float*)d_out);
}

// Round 15
// 221.381 us; speedup vs baseline: 1.0340x; 1.0340x over previous
//
#include <hip/hip_runtime.h>
#include <hip/hip_bf16.h>

// SIREN + Fourier-features fused forward, MI355X (gfx950). Round 15.
// = round 12 (203us best) with a DOUBLE-BUFFERED h tile: layer L reads
// tile[L&1], epilogue writes straight into tile[(L+1)&1]. Removes bar2
// entirely (writes overlap the tail of the k-loop; no same-tile WAR) ->
// ONE barrier per layer. k-loop is byte-identical to r12 (16 MFMAs per
// fetch round — the invariant r7/r8/r14 violated and regressed).
// Cost: 64KB LDS -> 2 blocks/CU (8 waves). Tests barrier-drain vs TLP.

typedef __attribute__((ext_vector_type(8))) short bf16x8;
typedef __attribute__((ext_vector_type(4))) float f32x4;

#define NTOTAL 262144
#define BM 64
#define HD 256
#define INV2PI 0.15915494309189535f

__device__ __forceinline__ unsigned short f2bf(float f) {
    unsigned int u = __float_as_uint(f);
    u += 0x7FFFu + ((u >> 16) & 1u);   // RNE (convert kernel only)
    return (unsigned short)(u >> 16);
}

// pack two floats -> 2xbf16 in one u32 (low = a, high = b), compiler-backed
__device__ __forceinline__ unsigned int pk2(float a, float b) {
    __hip_bfloat162 h = __float22bfloat162_rn(make_float2(a, b));
    union { __hip_bfloat162 h; unsigned int u; } c;
    c.h = h;
    return c.u;
}

__device__ __forceinline__ float sin_rev(float rev) {   // sin(2*pi*rev)
    return __builtin_amdgcn_sinf(__builtin_amdgcn_fractf(rev));
}

// swizzled byte offset into a [64][256] bf16 LDS tile (row stride 512B).
// XOR spans bits 4-7: bijective per row; write conflicts 2-way (free).
__device__ __forceinline__ int a_off(int r, int byte) {
    return r * 512 + (byte ^ ((r & 15) << 4));
}

// ---------------- kernel 1: weight conversion + fragment packing ----------------
// wb layout (bf16 elems): 5 layers x 65536, each as 128 fragments x 512 elems.
// fragidx = jt_global*8 + kt; within-fragment elem = (q*16 + r)*8 + t, where
// j = jt_global*16 + r, k = kt*32 + q*8 + t. Then Wf row-major 16x256 zero-pad.
// Layer-0 weights pre-scaled by sqrt(2) (Fourier feature scale folded in).
__global__ void convert_w(const float* __restrict__ W0, const float* __restrict__ Wh,
                          const float* __restrict__ Wf, unsigned short* __restrict__ wb) {
    const int i = blockIdx.x * 256 + threadIdx.x;      // grid 1280 -> 327680
    if (i < 327680) {
        const int l = i >> 16, rem = i & 65535;
        const int j = rem >> 8, k = rem & 255;
        const float v = (l == 0) ? W0[rem] * 1.41421356237309515f : Wh[i - 65536];
        const int jt = j >> 4, kt = k >> 5, q = (k >> 3) & 3, r = j & 15, t = k & 7;
        const int dst = (l << 16) + (((jt << 3) + kt) << 9) + (((q << 4) + r) << 3) + t;
        wb[dst] = f2bf(v);
    }
    if (i < 4096)
        wb[327680 + i] = (i < 512) ? f2bf(Wf[i]) : (unsigned short)0;
}

// ---------------- kernel 2: fused model ----------------
__global__ __launch_bounds__(256, 2) void siren_fused(
    const float* __restrict__ x, const float* __restrict__ scales,
    const float* __restrict__ Bm, const float* __restrict__ b0,
    const float* __restrict__ bh, const float* __restrict__ bfin,
    const unsigned short* __restrict__ wb, float* __restrict__ out) {

    __shared__ __align__(16) unsigned short A[2][BM * HD];   // 2 x 32KB

    const int tid  = threadIdx.x;
    const int lane = tid & 63;
    const int wid  = tid >> 6;          // wave 0..3 owns neurons wid*64..+63
    const int row0 = blockIdx.x * BM;
    const int arow = lane & 15;
    const int q    = lane >> 4;         // 0..3
    const int kq   = q * 8;

    // ---- preload layer-0 kt=0 W fragments (overlap Fourier stage) ----
    bf16x8 wfbuf[2][4];
    #pragma unroll
    for (int jt = 0; jt < 4; ++jt)
        wfbuf[0][jt] = *(const bf16x8*)(wb + (((wid * 4 + jt) << 3) << 9) + lane * 8);

    // ---- Fourier feature stage (fp32; sqrt2 folded into W0) -> tile 0 ----
    {
        const int r  = tid >> 2;            // 0..63
        const int c0 = (tid & 3) * 32;      // 32 freqs per thread
        const float* xr = x + (row0 + r) * 3;
        const float x0 = xr[0] * scales[0] * INV2PI;
        const float x1 = xr[1] * scales[1] * INV2PI;
        const float x2 = xr[2] * scales[2] * INV2PI;
        #pragma unroll
        for (int cc = 0; cc < 32; cc += 8) {
            const int c = c0 + cc;
            float sv[8], cv[8];
            #pragma unroll
            for (int t = 0; t < 8; ++t) {
                const float rev = x0 * Bm[c + t] + x1 * Bm[128 + c + t] + x2 * Bm[256 + c + t];
                const float fr  = __builtin_amdgcn_fractf(rev);
                sv[t] = __builtin_amdgcn_sinf(fr);
                cv[t] = __builtin_amdgcn_cosf(fr);
            }
            uint4 us, uc;
            us.x = pk2(sv[0], sv[1]); us.y = pk2(sv[2], sv[3]);
            us.z = pk2(sv[4], sv[5]); us.w = pk2(sv[6], sv[7]);
            uc.x = pk2(cv[0], cv[1]); uc.y = pk2(cv[2], cv[3]);
            uc.z = pk2(cv[4], cv[5]); uc.w = pk2(cv[6], cv[7]);
            *(uint4*)((char*)A[0] + a_off(r, 2 * c))         = us;
            *(uint4*)((char*)A[0] + a_off(r, 2 * (c + 128))) = uc;
        }
    }

    // ---- 5 dense layers: read tile[L&1], write tile[(L+1)&1], 1 barrier ----
    #pragma unroll 1
    for (int layer = 0; layer < 5; ++layer) {
        const unsigned short* Wl = wb + (layer << 16);
        const char* rd = (const char*)A[layer & 1];
        char*       wr = (char*)A[(layer + 1) & 1];

        __syncthreads();   // previous layer's writes (into rd) complete

        f32x4 acc[4][4];
        #pragma unroll
        for (int a = 0; a < 4; ++a)
            #pragma unroll
            for (int b = 0; b < 4; ++b)
                acc[a][b] = (f32x4)(0.0f);

        #pragma unroll
        for (int kt = 0; kt < 8; ++kt) {
            const int cur = kt & 1, nxt = cur ^ 1;
            bf16x8 hf[4];
            #pragma unroll
            for (int rt = 0; rt < 4; ++rt)
                hf[rt] = *(const bf16x8*)(rd + a_off(rt * 16 + arow, kt * 64 + q * 16));
            if (kt < 7) {
                #pragma unroll
                for (int jt = 0; jt < 4; ++jt)
                    wfbuf[nxt][jt] = *(const bf16x8*)(Wl +
                        ((((wid * 4 + jt) << 3) + kt + 1) << 9) + lane * 8);
            }
            #pragma unroll
            for (int jt = 0; jt < 4; ++jt)
                #pragma unroll
                for (int rt = 0; rt < 4; ++rt)
                    acc[jt][rt] = __builtin_amdgcn_mfma_f32_16x16x32_bf16(
                        wfbuf[cur][jt], hf[rt], acc[jt][rt], 0, 0, 0);
        }

        // prefetch next layer's kt=0 W fragments (overlaps epilogue)
        if (layer < 4) {
            const unsigned short* Wn = wb + ((layer + 1) << 16);
            #pragma unroll
            for (int jt = 0; jt < 4; ++jt)
                wfbuf[0][jt] = *(const bf16x8*)(Wn + (((wid * 4 + jt) << 3) << 9) + lane * 8);
        }

        // epilogue: sin(2*pi*(acc*s + b*s)) written DIRECTLY to the other tile
        const float s = (layer == 0) ? (30.0f * INV2PI) : INV2PI;
        const float* bias = (layer == 0) ? b0 : (bh + (layer - 1) * HD);
        #pragma unroll
        for (int jt = 0; jt < 4; ++jt) {
            const int jj = wid * 64 + jt * 16 + q * 4;   // 4 consecutive neurons
            float4 bv = *(const float4*)(bias + jj);
            bv.x *= s; bv.y *= s; bv.z *= s; bv.w *= s;
            #pragma unroll
            for (int rt = 0; rt < 4; ++rt) {
                const int r = rt * 16 + arow;
                const float s0 = sin_rev(fmaf(acc[jt][rt][0], s, bv.x));
                const float s1 = sin_rev(fmaf(acc[jt][rt][1], s, bv.y));
                const float s2 = sin_rev(fmaf(acc[jt][rt][2], s, bv.z));
                const float s3 = sin_rev(fmaf(acc[jt][rt][3], s, bv.w));
                uint2 val;
                val.x = pk2(s0, s1);
                val.y = pk2(s2, s3);
                *(uint2*)(wr + a_off(r, jj * 2)) = val;
            }
        }
    }

    __syncthreads();   // layer-4 writes into tile[1] complete

    // ---- final linear 256 -> 2, distributed: wave w handles rows w*16..+15 ----
    {
        const unsigned short* Wfp = wb + 327680;   // row-major [16][256], zero-padded
        const char* rd = (const char*)A[1];
        f32x4 acc = (f32x4)(0.0f);
        #pragma unroll
        for (int kt = 0; kt < 8; ++kt) {
            const bf16x8 ff = *(const bf16x8*)(Wfp + arow * HD + kt * 32 + kq);
            const bf16x8 hf = *(const bf16x8*)(rd + a_off(wid * 16 + arow, kt * 64 + q * 16));
            acc = __builtin_amdgcn_mfma_f32_16x16x32_bf16(ff, hf, acc, 0, 0, 0);
        }
        if (q == 0) {   // lanes 0-15 hold D rows j=0..3; j=0,1 are the two outputs
            const int rg = row0 + wid * 16 + arow;
            float2 o;
            o.x = acc[0] + bfin[0];
            o.y = acc[1] + bfin[1];
            *(float2*)(out + rg * 2) = o;
        }
    }
}

extern "C" void kernel_launch(void* const* d_in, const int* in_sizes, int n_in,
                              void* d_out, int out_size, void* d_ws, size_t ws_size,
                              hipStream_t stream) {
    (void)in_sizes; (void)n_in; (void)out_size; (void)ws_size;
    const float* x      = (const float*)d_in[0];
    const float* scales = (const float*)d_in[1];
    const float* Bm     = (const float*)d_in[2];
    const float* W0     = (const float*)d_in[3];
    const float* b0     = (const float*)d_in[4];
    const float* Wh     = (const float*)d_in[5];
    const float* bh     = (const float*)d_in[6];
    const float* Wf     = (const float*)d_in[7];
    const float* bf     = (const float*)d_in[8];
    unsigned short* wb  = (unsigned short*)d_ws;   // needs 663552 B

    hipLaunchKernelGGL(convert_w, dim3(1280), dim3(256), 0, stream, W0, Wh, Wf, wb);
    hipLaunchKernelGGL(siren_fused, dim3(NTOTAL / BM), dim3(256), 0, stream,
                       x, scales, Bm, b0, bh, bf, wb, (float*)d_out);
}

// Round 16
// 192.547 us; speedup vs baseline: 1.1888x; 1.1497x over previous
//
#include <hip/hip_runtime.h>
#include <hip/hip_bf16.h>

// SIREN + Fourier-features fused forward, MI355X (gfx950). Round 16.
// = round 12 (203us best) with the epilogue chain algebraically shortened:
//  (1) omega/2pi folded into packed W (layer0 also x sqrt2) at convert time,
//  (2) biases pre-scaled (b' = b*omega/2pi, f32 table in d_ws) and loaded as
//      the MFMA accumulator INIT (C-in = bias),
//  (3) fract dropped: v_sin_f32 domain is +-256 revolutions (internal
//      reduction); max |arg| here ~40 rev. Epilogue = v_sin + pack only.
// Structure (16 MFMAs/fetch round, 12 waves/CU, 2 barriers/layer) untouched —
// every structural deviation in r7-r15 regressed.

typedef __attribute__((ext_vector_type(8))) short bf16x8;
typedef __attribute__((ext_vector_type(4))) float f32x4;

#define NTOTAL 262144
#define BM 64
#define HD 256
#define INV2PI 0.15915494309189535f

__device__ __forceinline__ unsigned short f2bf(float f) {
    unsigned int u = __float_as_uint(f);
    u += 0x7FFFu + ((u >> 16) & 1u);   // RNE (convert kernel only)
    return (unsigned short)(u >> 16);
}

// pack two floats -> 2xbf16 in one u32 (low = a, high = b), compiler-backed
__device__ __forceinline__ unsigned int pk2(float a, float b) {
    __hip_bfloat162 h = __float22bfloat162_rn(make_float2(a, b));
    union { __hip_bfloat162 h; unsigned int u; } c;
    c.h = h;
    return c.u;
}

// swizzled byte offset into the [64][256] bf16 LDS tile (row stride 512B).
// XOR spans bits 4-7: bijective per row; write conflicts 2-way (free).
__device__ __forceinline__ int a_off(int r, int byte) {
    return r * 512 + (byte ^ ((r & 15) << 4));
}

// ---------------- kernel 1: weight conversion + fragment packing ----------------
// wb (bf16 elems): 5 layers x 65536 fragment-packed W' (pre-scaled by omega/2pi;
// layer0 also x sqrt2), then Wf row-major 16x256 zero-pad (elems 327680..331775),
// then 5x256 f32 scaled biases b' at byte offset 663552.
__global__ void convert_w(const float* __restrict__ W0, const float* __restrict__ Wh,
                          const float* __restrict__ Wf, const float* __restrict__ b0,
                          const float* __restrict__ bh, unsigned short* __restrict__ wb) {
    const int i = blockIdx.x * 256 + threadIdx.x;      // grid 1280 -> 327680
    if (i < 327680) {
        const int l = i >> 16, rem = i & 65535;
        const int j = rem >> 8, k = rem & 255;
        const float sc = (l == 0) ? (1.41421356237309515f * 30.0f * INV2PI) : INV2PI;
        const float v = ((l == 0) ? W0[rem] : Wh[i - 65536]) * sc;
        const int jt = j >> 4, kt = k >> 5, q = (k >> 3) & 3, r = j & 15, t = k & 7;
        const int dst = (l << 16) + (((jt << 3) + kt) << 9) + (((q << 4) + r) << 3) + t;
        wb[dst] = f2bf(v);
    }
    if (i < 4096)
        wb[327680 + i] = (i < 512) ? f2bf(Wf[i]) : (unsigned short)0;
    if (i < 1280) {   // scaled bias table (f32)
        const int l = i >> 8, j = i & 255;
        const float sc = (l == 0) ? (30.0f * INV2PI) : INV2PI;
        float* bsc = (float*)(wb + 331776);
        bsc[i] = ((l == 0) ? b0[j] : bh[i - 256]) * sc;
    }
}

// ---------------- kernel 2: fused model ----------------
__global__ __launch_bounds__(256, 3) void siren_fused(
    const float* __restrict__ x, const float* __restrict__ scales,
    const float* __restrict__ Bm, const float* __restrict__ bfin,
    const unsigned short* __restrict__ wb, float* __restrict__ out) {

    __shared__ __align__(16) unsigned short A[BM * HD];

    const int tid  = threadIdx.x;
    const int lane = tid & 63;
    const int wid  = tid >> 6;          // wave 0..3 owns neurons wid*64..+63
    const int row0 = blockIdx.x * BM;
    const int arow = lane & 15;
    const int q    = lane >> 4;         // 0..3
    const int kq   = q * 8;
    const float* bsc = (const float*)(wb + 331776);

    // ---- preload layer-0 kt=0 W fragments (overlap Fourier stage) ----
    bf16x8 wfbuf[2][4];
    #pragma unroll
    for (int jt = 0; jt < 4; ++jt)
        wfbuf[0][jt] = *(const bf16x8*)(wb + (((wid * 4 + jt) << 3) << 9) + lane * 8);

    // ---- Fourier feature stage (fp32; sqrt2 folded into W0'; no fract) ----
    {
        const int r  = tid >> 2;            // 0..63
        const int c0 = (tid & 3) * 32;      // 32 freqs per thread
        const float* xr = x + (row0 + r) * 3;
        const float x0 = xr[0] * scales[0] * INV2PI;
        const float x1 = xr[1] * scales[1] * INV2PI;
        const float x2 = xr[2] * scales[2] * INV2PI;
        #pragma unroll
        for (int cc = 0; cc < 32; cc += 8) {
            const int c = c0 + cc;
            float sv[8], cv[8];
            #pragma unroll
            for (int t = 0; t < 8; ++t) {
                const float rev = x0 * Bm[c + t] + x1 * Bm[128 + c + t] + x2 * Bm[256 + c + t];
                sv[t] = __builtin_amdgcn_sinf(rev);   // |rev| < ~50 rev, in-domain
                cv[t] = __builtin_amdgcn_cosf(rev);
            }
            uint4 us, uc;
            us.x = pk2(sv[0], sv[1]); us.y = pk2(sv[2], sv[3]);
            us.z = pk2(sv[4], sv[5]); us.w = pk2(sv[6], sv[7]);
            uc.x = pk2(cv[0], cv[1]); uc.y = pk2(cv[2], cv[3]);
            uc.z = pk2(cv[4], cv[5]); uc.w = pk2(cv[6], cv[7]);
            *(uint4*)((char*)A + a_off(r, 2 * c))         = us;
            *(uint4*)((char*)A + a_off(r, 2 * (c + 128))) = uc;
        }
    }

    // ---- 5 dense layers ----
    #pragma unroll 1
    for (int layer = 0; layer < 5; ++layer) {
        const unsigned short* Wl = wb + (layer << 16);
        const float* bl = bsc + layer * HD;

        __syncthreads();   // h tile ready

        // acc initialized with the scaled bias (C-in = b'): same math as
        // adding after, removes fma+bias handling from the epilogue.
        f32x4 acc[4][4];
        #pragma unroll
        for (int jt = 0; jt < 4; ++jt) {
            const float4 bv = *(const float4*)(bl + wid * 64 + jt * 16 + q * 4);
            #pragma unroll
            for (int rt = 0; rt < 4; ++rt) {
                acc[jt][rt][0] = bv.x; acc[jt][rt][1] = bv.y;
                acc[jt][rt][2] = bv.z; acc[jt][rt][3] = bv.w;
            }
        }

        #pragma unroll
        for (int kt = 0; kt < 8; ++kt) {
            const int cur = kt & 1, nxt = cur ^ 1;
            bf16x8 hf[4];
            #pragma unroll
            for (int rt = 0; rt < 4; ++rt)
                hf[rt] = *(const bf16x8*)((const char*)A +
                    a_off(rt * 16 + arow, kt * 64 + q * 16));
            if (kt < 7) {
                #pragma unroll
                for (int jt = 0; jt < 4; ++jt)
                    wfbuf[nxt][jt] = *(const bf16x8*)(Wl +
                        ((((wid * 4 + jt) << 3) + kt + 1) << 9) + lane * 8);
            }
            #pragma unroll
            for (int jt = 0; jt < 4; ++jt)
                #pragma unroll
                for (int rt = 0; rt < 4; ++rt)
                    acc[jt][rt] = __builtin_amdgcn_mfma_f32_16x16x32_bf16(
                        wfbuf[cur][jt], hf[rt], acc[jt][rt], 0, 0, 0);
        }

        __syncthreads();   // all reads of h done; safe to overwrite

        // prefetch next layer's kt=0 W fragments (overlaps epilogue)
        if (layer < 4) {
            const unsigned short* Wn = wb + ((layer + 1) << 16);
            #pragma unroll
            for (int jt = 0; jt < 4; ++jt)
                wfbuf[0][jt] = *(const bf16x8*)(Wn + (((wid * 4 + jt) << 3) << 9) + lane * 8);
        }

        // epilogue: h = sin(2*pi*acc) — bare v_sin + pack (bias/scale pre-folded)
        #pragma unroll
        for (int jt = 0; jt < 4; ++jt) {
            const int jj = wid * 64 + jt * 16 + q * 4;   // 4 consecutive neurons
            #pragma unroll
            for (int rt = 0; rt < 4; ++rt) {
                const int r = rt * 16 + arow;
                const float s0 = __builtin_amdgcn_sinf(acc[jt][rt][0]);
                const float s1 = __builtin_amdgcn_sinf(acc[jt][rt][1]);
                const float s2 = __builtin_amdgcn_sinf(acc[jt][rt][2]);
                const float s3 = __builtin_amdgcn_sinf(acc[jt][rt][3]);
                uint2 val;
                val.x = pk2(s0, s1);
                val.y = pk2(s2, s3);
                *(uint2*)((char*)A + a_off(r, jj * 2)) = val;
            }
        }
    }

    __syncthreads();   // final h ready

    // ---- final linear 256 -> 2, distributed: wave w handles rows w*16..+15 ----
    {
        const unsigned short* Wfp = wb + 327680;   // row-major [16][256], zero-padded
        f32x4 acc = (f32x4)(0.0f);
        #pragma unroll
        for (int kt = 0; kt < 8; ++kt) {
            const bf16x8 ff = *(const bf16x8*)(Wfp + arow * HD + kt * 32 + kq);
            const bf16x8 hf = *(const bf16x8*)((const char*)A +
                a_off(wid * 16 + arow, kt * 64 + q * 16));
            acc = __builtin_amdgcn_mfma_f32_16x16x32_bf16(ff, hf, acc, 0, 0, 0);
        }
        if (q == 0) {   // lanes 0-15 hold D rows j=0..3; j=0,1 are the two outputs
            const int rg = row0 + wid * 16 + arow;
            float2 o;
            o.x = acc[0] + bfin[0];
            o.y = acc[1] + bfin[1];
            *(float2*)(out + rg * 2) = o;
        }
    }
}

extern "C" void kernel_launch(void* const* d_in, const int* in_sizes, int n_in,
                              void* d_out, int out_size, void* d_ws, size_t ws_size,
                              hipStream_t stream) {
    (void)in_sizes; (void)n_in; (void)out_size; (void)ws_size;
    const float* x      = (const float*)d_in[0];
    const float* scales = (const float*)d_in[1];
    const float* Bm     = (const float*)d_in[2];
    const float* W0     = (const float*)d_in[3];
    const float* b0     = (const float*)d_in[4];
    const float* Wh     = (const float*)d_in[5];
    const float* bh     = (const float*)d_in[6];
    const float* Wf     = (const float*)d_in[7];
    const float* bf     = (const float*)d_in[8];
    unsigned short* wb  = (unsigned short*)d_ws;   // needs 668672 B

    hipLaunchKernelGGL(convert_w, dim3(1280), dim3(256), 0, stream,
                       W0, Wh, Wf, b0, bh, wb);
    hipLaunchKernelGGL(siren_fused, dim3(NTOTAL / BM), dim3(256), 0, stream,
                       x, scales, Bm, bf, wb, (float*)d_out);
}